// Round 1
// baseline (422.348 us; speedup 1.0000x reference)
//
#include <hip/hip_runtime.h>
#include <hip/hip_bf16.h>
#include <cstdint>
#include <cstddef>

// Problem: N=8192 queries, M=16384 cache, D=512, K=512 (all f32 in/out).
// out = where(min_dist(x, cache_emb) <= 0.01, cache_out[argmin], x@W+b)
//
// Strategy:
//  1) cast x / cache_emb to bf16 (+ row sumsq in f32)
//  2) bf16 MFMA GEMM of x @ cache_emb^T with fused per-row (min d2, argmin)
//     epilogue -> packed u64 keys via atomicMin (no [N,M] materialization)
//  3) bf16 MFMA GEMM x @ W + b with fused cache-select epilogue

#define NQ 8192
#define MC 16384
#define DD 512
#define KK 512

typedef float f32x4 __attribute__((ext_vector_type(4)));
typedef __bf16 bf16x8 __attribute__((ext_vector_type(8)));
typedef short short8 __attribute__((ext_vector_type(8)));

// ---- workspace layout (bytes) ----
#define MIN_OFF 0u
#define X2_OFF (64u * 1024u)
#define C2_OFF (X2_OFF + 32u * 1024u)
#define XB_OFF (C2_OFF + 64u * 1024u)
#define CB_OFF (XB_OFF + (unsigned)NQ * DD * 2u)
#define WT_OFF (CB_OFF + (unsigned)MC * DD * 2u)
// total need ~= 25.9 MB

__device__ __forceinline__ short f2bf(float f) {
  // round-to-nearest-even f32 -> bf16 (inputs are finite)
  unsigned int u = __float_as_uint(f);
  u += 0x7FFFu + ((u >> 16) & 1u);
  return (short)(u >> 16);
}

__device__ __forceinline__ void gload_lds16(const void* g, void* l) {
  // async global->LDS, 16B per lane; LDS dest is wave-uniform base + lane*16
  __builtin_amdgcn_global_load_lds(
      (__attribute__((address_space(1))) void*)(g),
      (__attribute__((address_space(3))) void*)(l), 16, 0, 0);
}

// ---- cast rows to bf16 + compute row sum-of-squares (one wave per row) ----
__global__ __launch_bounds__(256) void prep_rows(const float* __restrict__ src,
                                                 short* __restrict__ dstb,
                                                 float* __restrict__ dst2) {
  const int lane = threadIdx.x & 63;
  const size_t row = (size_t)blockIdx.x * 4 + (threadIdx.x >> 6);
  const float4* p = (const float4*)(src + row * DD + lane * 8);
  float4 v0 = p[0], v1 = p[1];
  float s = v0.x * v0.x + v0.y * v0.y + v0.z * v0.z + v0.w * v0.w +
            v1.x * v1.x + v1.y * v1.y + v1.z * v1.z + v1.w * v1.w;
  short8 o;
  o[0] = f2bf(v0.x); o[1] = f2bf(v0.y); o[2] = f2bf(v0.z); o[3] = f2bf(v0.w);
  o[4] = f2bf(v1.x); o[5] = f2bf(v1.y); o[6] = f2bf(v1.z); o[7] = f2bf(v1.w);
  *(short8*)(dstb + row * DD + lane * 8) = o;
#pragma unroll
  for (int m = 32; m >= 1; m >>= 1) s += __shfl_xor(s, m, 64);
  if (lane == 0) dst2[row] = s;
}

// ---- transpose-cast W[d][j] (f32) -> wt[j][d] (bf16) ----
__global__ __launch_bounds__(256) void prep_w(const float* __restrict__ W,
                                              short* __restrict__ wt) {
  __shared__ float t[64][65];
  const int bx = blockIdx.x, by = blockIdx.y;  // bx: j-tile, by: d-tile
#pragma unroll
  for (int i = 0; i < 16; ++i) {
    int idx = i * 256 + threadIdx.x;
    int r = idx >> 6, c = idx & 63;  // r: d-local, c: j-local
    t[r][c] = W[(size_t)(by * 64 + r) * KK + bx * 64 + c];
  }
  __syncthreads();
#pragma unroll
  for (int i = 0; i < 16; ++i) {
    int idx = i * 256 + threadIdx.x;
    int r = idx >> 6, c = idx & 63;  // r: j-local, c: d-local
    wt[(size_t)(bx * 64 + r) * DD + by * 64 + c] = f2bf(t[c][r]);
  }
}

// ---- main GEMM: S = x @ cache_emb^T with fused per-row min(d2) epilogue ----
// 128x128 tile, 4 waves as 2x2 of 64x64, mfma 16x16x32 bf16, BK=64, 8 K-iters
__global__ __launch_bounds__(256) void gemm_min(
    const short* __restrict__ xb, const short* __restrict__ cb,
    const float* __restrict__ x2, const float* __restrict__ c2,
    unsigned long long* __restrict__ mink) {
  __shared__ short lA[128 * 64];
  __shared__ short lB[128 * 64];
  const int tid = threadIdx.x;
  const int lane = tid & 63;
  const int wid = tid >> 6;
  const int wr = wid >> 1, wc = wid & 1;
  const int cl = lane & 15, cr = lane >> 4;
  const size_t row0 = (size_t)blockIdx.y * 128;
  const size_t col0 = (size_t)blockIdx.x * 128;

  f32x4 acc[4][4];
#pragma unroll
  for (int m = 0; m < 4; ++m)
#pragma unroll
    for (int n = 0; n < 4; ++n) acc[m][n] = (f32x4)0.0f;

  for (int kt = 0; kt < DD / 64; ++kt) {
    const int k0 = kt * 64;
#pragma unroll
    for (int i = 0; i < 4; ++i) {
      const int cb0 = wid * 256 + i * 64;  // wave-uniform chunk base
      const int chunk = cb0 + lane;
      const int r = chunk >> 3, kc = chunk & 7;  // [128][64] linear, 8 chunks/row
      gload_lds16(xb + (row0 + r) * DD + k0 + kc * 8, (char*)lA + cb0 * 16);
      gload_lds16(cb + (col0 + r) * DD + k0 + kc * 8, (char*)lB + cb0 * 16);
    }
    __syncthreads();
#pragma unroll
    for (int ks = 0; ks < 2; ++ks) {
      bf16x8 a[4], b[4];
#pragma unroll
      for (int m = 0; m < 4; ++m)
        a[m] = *(const bf16x8*)(lA + (wr * 64 + m * 16 + cl) * 64 + ks * 32 + cr * 8);
#pragma unroll
      for (int n = 0; n < 4; ++n)
        b[n] = *(const bf16x8*)(lB + (wc * 64 + n * 16 + cl) * 64 + ks * 32 + cr * 8);
#pragma unroll
      for (int m = 0; m < 4; ++m)
#pragma unroll
        for (int n = 0; n < 4; ++n)
          acc[m][n] = __builtin_amdgcn_mfma_f32_16x16x32_bf16(a[m], b[n], acc[m][n], 0, 0, 0);
    }
    __syncthreads();
  }

  // epilogue: d2 = x2 + c2 - 2S, clamp >= 0, pack (d2bits, col), reduce
  float c2v[4];
#pragma unroll
  for (int n = 0; n < 4; ++n) c2v[n] = c2[col0 + wc * 64 + n * 16 + cl];

#pragma unroll
  for (int m = 0; m < 4; ++m) {
#pragma unroll
    for (int r = 0; r < 4; ++r) {
      const size_t row = row0 + wr * 64 + m * 16 + cr * 4 + r;
      const float xv = x2[row];
      unsigned long long best = ~0ull;
#pragma unroll
      for (int n = 0; n < 4; ++n) {
        float d2 = fmaxf(xv + c2v[n] - 2.0f * acc[m][n][r], 0.0f);
        unsigned int col = (unsigned int)(col0 + wc * 64 + n * 16 + cl);
        unsigned long long key =
            ((unsigned long long)__float_as_uint(d2) << 32) | col;
        if (key < best) best = key;
      }
      // butterfly min over the 16 lanes sharing this row (masks stay in-group)
#pragma unroll
      for (int msk = 8; msk >= 1; msk >>= 1) {
        unsigned long long o = __shfl_xor(best, msk, 64);
        if (o < best) best = o;
      }
      if (cl == 0) atomicMin(&mink[row], best);
    }
  }
}

// ---- fallback GEMM: out = x @ W + b, with cache-select epilogue ----
__global__ __launch_bounds__(256) void gemm_out(
    const short* __restrict__ xb, const short* __restrict__ wt,
    const float* __restrict__ bias, const float* __restrict__ cache_out,
    const unsigned long long* __restrict__ mink, float* __restrict__ out) {
  __shared__ short lA[128 * 64];
  __shared__ short lB[128 * 64];
  const int tid = threadIdx.x;
  const int lane = tid & 63;
  const int wid = tid >> 6;
  const int wr = wid >> 1, wc = wid & 1;
  const int cl = lane & 15, cr = lane >> 4;
  const size_t row0 = (size_t)blockIdx.y * 128;
  const size_t col0 = (size_t)blockIdx.x * 128;

  f32x4 acc[4][4];
#pragma unroll
  for (int m = 0; m < 4; ++m)
#pragma unroll
    for (int n = 0; n < 4; ++n) acc[m][n] = (f32x4)0.0f;

  for (int kt = 0; kt < DD / 64; ++kt) {
    const int k0 = kt * 64;
#pragma unroll
    for (int i = 0; i < 4; ++i) {
      const int cb0 = wid * 256 + i * 64;
      const int chunk = cb0 + lane;
      const int r = chunk >> 3, kc = chunk & 7;
      gload_lds16(xb + (row0 + r) * DD + k0 + kc * 8, (char*)lA + cb0 * 16);
      gload_lds16(wt + (col0 + r) * DD + k0 + kc * 8, (char*)lB + cb0 * 16);
    }
    __syncthreads();
#pragma unroll
    for (int ks = 0; ks < 2; ++ks) {
      bf16x8 a[4], b[4];
#pragma unroll
      for (int m = 0; m < 4; ++m)
        a[m] = *(const bf16x8*)(lA + (wr * 64 + m * 16 + cl) * 64 + ks * 32 + cr * 8);
#pragma unroll
      for (int n = 0; n < 4; ++n)
        b[n] = *(const bf16x8*)(lB + (wc * 64 + n * 16 + cl) * 64 + ks * 32 + cr * 8);
#pragma unroll
      for (int m = 0; m < 4; ++m)
#pragma unroll
        for (int n = 0; n < 4; ++n)
          acc[m][n] = __builtin_amdgcn_mfma_f32_16x16x32_bf16(a[m], b[n], acc[m][n], 0, 0, 0);
    }
    __syncthreads();
  }

#pragma unroll
  for (int m = 0; m < 4; ++m) {
#pragma unroll
    for (int r = 0; r < 4; ++r) {
      const size_t row = row0 + wr * 64 + m * 16 + cr * 4 + r;
      const unsigned long long key = mink[row];
      const float d2 = __uint_as_float((unsigned int)(key >> 32));
      const bool usec = (d2 <= 1e-4f);  // dist <= 0.01
      const unsigned int idx = (unsigned int)(key & 0xFFFFFFFFu);
#pragma unroll
      for (int n = 0; n < 4; ++n) {
        const size_t col = col0 + wc * 64 + n * 16 + cl;
        float v = acc[m][n][r] + bias[col];
        if (usec) v = cache_out[(size_t)idx * KK + col];
        out[row * KK + col] = v;
      }
    }
  }
}

extern "C" void kernel_launch(void* const* d_in, const int* in_sizes, int n_in,
                              void* d_out, int out_size, void* d_ws,
                              size_t ws_size, hipStream_t stream) {
  const float* x = (const float*)d_in[0];
  const float* cache_emb = (const float*)d_in[1];
  const float* cache_out = (const float*)d_in[2];
  const float* W = (const float*)d_in[3];
  const float* bias = (const float*)d_in[4];
  float* out = (float*)d_out;
  char* ws = (char*)d_ws;

  unsigned long long* mink = (unsigned long long*)(ws + MIN_OFF);
  float* x2 = (float*)(ws + X2_OFF);
  float* c2 = (float*)(ws + C2_OFF);
  short* xb = (short*)(ws + XB_OFF);
  short* cb = (short*)(ws + CB_OFF);
  short* wt = (short*)(ws + WT_OFF);

  hipMemsetAsync(mink, 0xFF, NQ * sizeof(unsigned long long), stream);
  prep_rows<<<NQ / 4, 256, 0, stream>>>(x, xb, x2);
  prep_rows<<<MC / 4, 256, 0, stream>>>(cache_emb, cb, c2);
  prep_w<<<dim3(KK / 64, DD / 64), 256, 0, stream>>>(W, wt);
  gemm_min<<<dim3(MC / 128, NQ / 128), 256, 0, stream>>>(xb, cb, x2, c2, mink);
  gemm_out<<<dim3(KK / 128, NQ / 128), 256, 0, stream>>>(xb, wt, bias,
                                                         cache_out, mink, out);
}

// Round 2
// 376.787 us; speedup vs baseline: 1.1209x; 1.1209x over previous
//
#include <hip/hip_runtime.h>
#include <hip/hip_bf16.h>
#include <cstdint>
#include <cstddef>

// out = where(min_dist(x, cache_emb) <= 0.01, cache_out[argmin], x@W+b)
// N=8192, M=16384, D=512, K=512, f32 in/out.
// gemm_min: 256x256 tile, 8-phase counted-vmcnt schedule (T1+T2+T3+T4+T5).

#define NQ 8192
#define MC 16384
#define DD 512
#define KK 512

typedef float f32x4 __attribute__((ext_vector_type(4)));
typedef __bf16 bf16x8 __attribute__((ext_vector_type(8)));
typedef short short8 __attribute__((ext_vector_type(8)));

// ---- workspace layout (bytes) ----
#define MIN_OFF 0u
#define X2_OFF (64u * 1024u)
#define C2_OFF (X2_OFF + 32u * 1024u)
#define XB_OFF (C2_OFF + 64u * 1024u)
#define CB_OFF (XB_OFF + (unsigned)NQ * DD * 2u)
#define WT_OFF (CB_OFF + (unsigned)MC * DD * 2u)

__device__ __forceinline__ short f2bf(float f) {
  unsigned int u = __float_as_uint(f);
  u += 0x7FFFu + ((u >> 16) & 1u);
  return (short)(u >> 16);
}

__device__ __forceinline__ void gload_lds16(const void* g, void* l) {
  __builtin_amdgcn_global_load_lds(
      (__attribute__((address_space(1))) void*)(g),
      (__attribute__((address_space(3))) void*)(l), 16, 0, 0);
}

// ---- cast rows to bf16 + row sum-of-squares ----
__global__ __launch_bounds__(256) void prep_rows(const float* __restrict__ src,
                                                 short* __restrict__ dstb,
                                                 float* __restrict__ dst2) {
  const int lane = threadIdx.x & 63;
  const size_t row = (size_t)blockIdx.x * 4 + (threadIdx.x >> 6);
  const float4* p = (const float4*)(src + row * DD + lane * 8);
  float4 v0 = p[0], v1 = p[1];
  float s = v0.x * v0.x + v0.y * v0.y + v0.z * v0.z + v0.w * v0.w +
            v1.x * v1.x + v1.y * v1.y + v1.z * v1.z + v1.w * v1.w;
  short8 o;
  o[0] = f2bf(v0.x); o[1] = f2bf(v0.y); o[2] = f2bf(v0.z); o[3] = f2bf(v0.w);
  o[4] = f2bf(v1.x); o[5] = f2bf(v1.y); o[6] = f2bf(v1.z); o[7] = f2bf(v1.w);
  *(short8*)(dstb + row * DD + lane * 8) = o;
#pragma unroll
  for (int m = 32; m >= 1; m >>= 1) s += __shfl_xor(s, m, 64);
  if (lane == 0) dst2[row] = s;
}

// ---- transpose-cast W[d][j] -> wt[j][d] (bf16) ----
__global__ __launch_bounds__(256) void prep_w(const float* __restrict__ W,
                                              short* __restrict__ wt) {
  __shared__ float t[64][65];
  const int bx = blockIdx.x, by = blockIdx.y;
#pragma unroll
  for (int i = 0; i < 16; ++i) {
    int idx = i * 256 + threadIdx.x;
    int r = idx >> 6, c = idx & 63;
    t[r][c] = W[(size_t)(by * 64 + r) * KK + bx * 64 + c];
  }
  __syncthreads();
#pragma unroll
  for (int i = 0; i < 16; ++i) {
    int idx = i * 256 + threadIdx.x;
    int r = idx >> 6, c = idx & 63;
    wt[(size_t)(bx * 64 + r) * DD + by * 64 + c] = f2bf(t[c][r]);
  }
}

// ---- stage one 128x64 half-tile (linear LDS dest, inverse-swizzled src) ----
// physical chunk p = wid*128 + j*64 + lane; row r = p>>3; holds logical
// k-chunk (p&7)^(r&7)  ->  ds_read applies the same XOR (T2 st-swizzle).
__device__ __forceinline__ void stage_half(const short* __restrict__ src,
                                           size_t grow0, int k0, short* lhalf,
                                           int wid, int lane) {
#pragma unroll
  for (int j = 0; j < 2; ++j) {
    const int pch = wid * 128 + j * 64 + lane;
    const int r = pch >> 3;
    const int c = (pch & 7) ^ (r & 7);
    gload_lds16(src + (grow0 + (size_t)r) * DD + k0 + c * 8,
                (char*)lhalf + (size_t)(wid * 128 + j * 64) * 16);
  }
}

__device__ __forceinline__ bf16x8 ld_frag(const short* lhalf, int row, int ks,
                                          int cr) {
  const int c = (ks * 4 + cr) ^ (row & 7);
  return *(const bf16x8*)(lhalf + row * 64 + c * 8);
}

// ---- main GEMM: 256x256 tile, 8 waves (2Mx4N), 8-phase, fused min epilogue --
__global__ __launch_bounds__(512, 2) void gemm_min(
    const short* __restrict__ xb, const short* __restrict__ cb,
    const float* __restrict__ x2, const float* __restrict__ c2,
    unsigned long long* __restrict__ mink) {
  __shared__ short L[2][2][2][8192];  // [buf][A/B][half][128*64] = 128 KiB
  const int tid = threadIdx.x;
  const int lane = tid & 63;
  const int wid = tid >> 6;
  const int wr = wid >> 2, wc = wid & 3;   // 2x4 wave grid, per-wave 128x64
  const int cl = lane & 15, cr = lane >> 4;

  // bijective XCD swizzle: nwg=2048 divisible by 8
  const int bid = blockIdx.x;
  const int swz = (bid & 7) * 256 + (bid >> 3);
  const int bx = swz & 63, by = swz >> 6;
  const size_t row0 = (size_t)by * 256;
  const size_t col0 = (size_t)bx * 256;

  f32x4 acc[8][4];
#pragma unroll
  for (int m = 0; m < 8; ++m)
#pragma unroll
    for (int n = 0; n < 4; ++n) acc[m][n] = (f32x4)0.0f;

  // prologue: 7 half-tiles in steady-state issue order, then vmcnt(6)
  stage_half(cb, col0, 0, &L[0][1][0][0], wid, lane);         // B0(0)
  stage_half(xb, row0, 0, &L[0][0][0][0], wid, lane);         // A0(0)
  stage_half(xb, row0 + 128, 0, &L[0][0][1][0], wid, lane);   // A1(0)
  stage_half(cb, col0 + 128, 0, &L[0][1][1][0], wid, lane);   // B1(0)
  stage_half(cb, col0, 64, &L[1][1][0][0], wid, lane);        // B0(1)
  stage_half(xb, row0, 64, &L[1][0][0][0], wid, lane);        // A0(1)
  stage_half(xb, row0 + 128, 64, &L[1][0][1][0], wid, lane);  // A1(1)
  asm volatile("s_waitcnt vmcnt(6)" ::: "memory");
  __builtin_amdgcn_s_barrier();

  for (int t = 0; t < 8; ++t) {
    const int p = t & 1;
    const short* lA = &L[p][0][wr][0];
    const short* lB = &L[p][1][wc >> 1][0];
    const int brow = (wc & 1) * 64;
    const int k1 = ((t + 1) & 7) * 64;
    const int k2 = ((t + 2) & 7) * 64;

    bf16x8 aLo[4][2], aHi[4][2], bLo[2][2], bHi[2][2];

    // -- phase A: read A-lo + B-lo; issue B1(t+1); MFMA quad (lo,lo) --
#pragma unroll
    for (int m = 0; m < 4; ++m)
#pragma unroll
      for (int ks = 0; ks < 2; ++ks)
        aLo[m][ks] = ld_frag(lA, m * 16 + cl, ks, cr);
#pragma unroll
    for (int n = 0; n < 2; ++n)
#pragma unroll
      for (int ks = 0; ks < 2; ++ks)
        bLo[n][ks] = ld_frag(lB, brow + n * 16 + cl, ks, cr);
    stage_half(cb, col0 + 128, k1, &L[p ^ 1][1][1][0], wid, lane);
    __builtin_amdgcn_s_barrier();
    asm volatile("s_waitcnt lgkmcnt(0)" ::: "memory");
    __builtin_amdgcn_sched_barrier(0);
    __builtin_amdgcn_s_setprio(1);
#pragma unroll
    for (int m = 0; m < 4; ++m)
#pragma unroll
      for (int n = 0; n < 2; ++n)
#pragma unroll
        for (int ks = 0; ks < 2; ++ks)
          acc[m][n] = __builtin_amdgcn_mfma_f32_16x16x32_bf16(
              aLo[m][ks], bLo[n][ks], acc[m][n], 0, 0, 0);
    __builtin_amdgcn_s_setprio(0);
    __builtin_amdgcn_s_barrier();

    // -- phase B: read A-hi; issue B0(t+2); MFMA quad (hi,lo) --
#pragma unroll
    for (int m = 0; m < 4; ++m)
#pragma unroll
      for (int ks = 0; ks < 2; ++ks)
        aHi[m][ks] = ld_frag(lA, 64 + m * 16 + cl, ks, cr);
    stage_half(cb, col0, k2, &L[p][1][0][0], wid, lane);
    __builtin_amdgcn_s_barrier();
    asm volatile("s_waitcnt lgkmcnt(0)" ::: "memory");
    __builtin_amdgcn_sched_barrier(0);
    __builtin_amdgcn_s_setprio(1);
#pragma unroll
    for (int m = 0; m < 4; ++m)
#pragma unroll
      for (int n = 0; n < 2; ++n)
#pragma unroll
        for (int ks = 0; ks < 2; ++ks)
          acc[4 + m][n] = __builtin_amdgcn_mfma_f32_16x16x32_bf16(
              aHi[m][ks], bLo[n][ks], acc[4 + m][n], 0, 0, 0);
    __builtin_amdgcn_s_setprio(0);
    __builtin_amdgcn_s_barrier();

    // -- phase C: read B-hi; issue A0(t+2); MFMA quad (lo,hi) --
#pragma unroll
    for (int n = 0; n < 2; ++n)
#pragma unroll
      for (int ks = 0; ks < 2; ++ks)
        bHi[n][ks] = ld_frag(lB, brow + 32 + n * 16 + cl, ks, cr);
    stage_half(xb, row0, k2, &L[p][0][0][0], wid, lane);
    __builtin_amdgcn_s_barrier();
    asm volatile("s_waitcnt lgkmcnt(0)" ::: "memory");
    __builtin_amdgcn_sched_barrier(0);
    __builtin_amdgcn_s_setprio(1);
#pragma unroll
    for (int m = 0; m < 4; ++m)
#pragma unroll
      for (int n = 0; n < 2; ++n)
#pragma unroll
        for (int ks = 0; ks < 2; ++ks)
          acc[m][2 + n] = __builtin_amdgcn_mfma_f32_16x16x32_bf16(
              aLo[m][ks], bHi[n][ks], acc[m][2 + n], 0, 0, 0);
    __builtin_amdgcn_s_setprio(0);
    __builtin_amdgcn_s_barrier();

    // -- phase D: issue A1(t+2); vmcnt(6) gates tile t+1; MFMA quad (hi,hi) --
    stage_half(xb, row0 + 128, k2, &L[p][0][1][0], wid, lane);
    asm volatile("s_waitcnt vmcnt(6)" ::: "memory");
    __builtin_amdgcn_s_barrier();
    __builtin_amdgcn_s_setprio(1);
#pragma unroll
    for (int m = 0; m < 4; ++m)
#pragma unroll
      for (int n = 0; n < 2; ++n)
#pragma unroll
        for (int ks = 0; ks < 2; ++ks)
          acc[4 + m][2 + n] = __builtin_amdgcn_mfma_f32_16x16x32_bf16(
              aHi[m][ks], bHi[n][ks], acc[4 + m][2 + n], 0, 0, 0);
    __builtin_amdgcn_s_setprio(0);
    __builtin_amdgcn_s_barrier();
  }

  asm volatile("s_waitcnt vmcnt(0)" ::: "memory");  // drain wrapped prefetches

  // epilogue: d2 = x2 + c2 - 2S; pack (d2bits, col); reduce; atomicMin
  float c2v[4];
#pragma unroll
  for (int n = 0; n < 4; ++n) c2v[n] = c2[col0 + wc * 64 + n * 16 + cl];
#pragma unroll
  for (int m = 0; m < 8; ++m) {
#pragma unroll
    for (int r = 0; r < 4; ++r) {
      const size_t row = row0 + wr * 128 + m * 16 + cr * 4 + r;
      const float xv = x2[row];
      unsigned long long best = ~0ull;
#pragma unroll
      for (int n = 0; n < 4; ++n) {
        float d2 = fmaxf(xv + c2v[n] - 2.0f * acc[m][n][r], 0.0f);
        unsigned int col = (unsigned int)(col0 + wc * 64 + n * 16 + cl);
        unsigned long long key =
            ((unsigned long long)__float_as_uint(d2) << 32) | col;
        best = key < best ? key : best;
      }
#pragma unroll
      for (int msk = 8; msk >= 1; msk >>= 1) {
        unsigned long long o = __shfl_xor(best, msk, 64);
        best = o < best ? o : best;
      }
      if (cl == 0) atomicMin(&mink[row], best);
    }
  }
}

// ---- fallback GEMM: out = x @ W + b, cache-select epilogue (unchanged) ----
__global__ __launch_bounds__(256) void gemm_out(
    const short* __restrict__ xb, const short* __restrict__ wt,
    const float* __restrict__ bias, const float* __restrict__ cache_out,
    const unsigned long long* __restrict__ mink, float* __restrict__ out) {
  __shared__ short lA[128 * 64];
  __shared__ short lB[128 * 64];
  const int tid = threadIdx.x;
  const int lane = tid & 63;
  const int wid = tid >> 6;
  const int wr = wid >> 1, wc = wid & 1;
  const int cl = lane & 15, cr = lane >> 4;
  const size_t row0 = (size_t)blockIdx.y * 128;
  const size_t col0 = (size_t)blockIdx.x * 128;

  f32x4 acc[4][4];
#pragma unroll
  for (int m = 0; m < 4; ++m)
#pragma unroll
    for (int n = 0; n < 4; ++n) acc[m][n] = (f32x4)0.0f;

  for (int kt = 0; kt < DD / 64; ++kt) {
    const int k0 = kt * 64;
#pragma unroll
    for (int i = 0; i < 4; ++i) {
      const int cb0 = wid * 256 + i * 64;
      const int chunk = cb0 + lane;
      const int r = chunk >> 3, kc = chunk & 7;
      gload_lds16(xb + (row0 + r) * DD + k0 + kc * 8, (char*)lA + cb0 * 16);
      gload_lds16(wt + (col0 + r) * DD + k0 + kc * 8, (char*)lB + cb0 * 16);
    }
    __syncthreads();
#pragma unroll
    for (int ks = 0; ks < 2; ++ks) {
      bf16x8 a[4], b[4];
#pragma unroll
      for (int m = 0; m < 4; ++m)
        a[m] = *(const bf16x8*)(lA + (wr * 64 + m * 16 + cl) * 64 + ks * 32 + cr * 8);
#pragma unroll
      for (int n = 0; n < 4; ++n)
        b[n] = *(const bf16x8*)(lB + (wc * 64 + n * 16 + cl) * 64 + ks * 32 + cr * 8);
#pragma unroll
      for (int m = 0; m < 4; ++m)
#pragma unroll
        for (int n = 0; n < 4; ++n)
          acc[m][n] = __builtin_amdgcn_mfma_f32_16x16x32_bf16(a[m], b[n], acc[m][n], 0, 0, 0);
    }
    __syncthreads();
  }

#pragma unroll
  for (int m = 0; m < 4; ++m) {
#pragma unroll
    for (int r = 0; r < 4; ++r) {
      const size_t row = row0 + wr * 64 + m * 16 + cr * 4 + r;
      const unsigned long long key = mink[row];
      const float d2 = __uint_as_float((unsigned int)(key >> 32));
      const bool usec = (d2 <= 1e-4f);
      const unsigned int idx = (unsigned int)(key & 0xFFFFFFFFu);
#pragma unroll
      for (int n = 0; n < 4; ++n) {
        const size_t col = col0 + wc * 64 + n * 16 + cl;
        float v = acc[m][n][r] + bias[col];
        if (usec) v = cache_out[(size_t)idx * KK + col];
        out[row * KK + col] = v;
      }
    }
  }
}

extern "C" void kernel_launch(void* const* d_in, const int* in_sizes, int n_in,
                              void* d_out, int out_size, void* d_ws,
                              size_t ws_size, hipStream_t stream) {
  const float* x = (const float*)d_in[0];
  const float* cache_emb = (const float*)d_in[1];
  const float* cache_out = (const float*)d_in[2];
  const float* W = (const float*)d_in[3];
  const float* bias = (const float*)d_in[4];
  float* out = (float*)d_out;
  char* ws = (char*)d_ws;

  unsigned long long* mink = (unsigned long long*)(ws + MIN_OFF);
  float* x2 = (float*)(ws + X2_OFF);
  float* c2 = (float*)(ws + C2_OFF);
  short* xb = (short*)(ws + XB_OFF);
  short* cb = (short*)(ws + CB_OFF);
  short* wt = (short*)(ws + WT_OFF);

  hipMemsetAsync(mink, 0xFF, NQ * sizeof(unsigned long long), stream);
  prep_rows<<<NQ / 4, 256, 0, stream>>>(x, xb, x2);
  prep_rows<<<MC / 4, 256, 0, stream>>>(cache_emb, cb, c2);
  prep_w<<<dim3(KK / 64, DD / 64), 256, 0, stream>>>(W, wt);
  gemm_min<<<(NQ / 256) * (MC / 256), 512, 0, stream>>>(xb, cb, x2, c2, mink);
  gemm_out<<<dim3(KK / 128, NQ / 128), 256, 0, stream>>>(xb, wt, bias,
                                                         cache_out, mink, out);
}

// Round 3
// 242.844 us; speedup vs baseline: 1.7392x; 1.5516x over previous
//
#include <hip/hip_runtime.h>
#include <hip/hip_bf16.h>
#include <cstdint>
#include <cstddef>

// out = where(min_dist(x, cache_emb) <= 0.01, cache_out[argmin], x@W+b)
// N=8192, M=16384, D=512, K=512, f32 in/out.
// gemm_min: 256x256 tile, 8-phase counted-vmcnt schedule (T1+T2+T3+T4+T5),
// race-safe prefetch placement, contention-free argmin reduction.

#define NQ 8192
#define MC 16384
#define DD 512
#define KK 512

typedef float f32x4 __attribute__((ext_vector_type(4)));
typedef __bf16 bf16x8 __attribute__((ext_vector_type(8)));
typedef short short8 __attribute__((ext_vector_type(8)));

// ---- workspace layout (bytes) ----
#define MIN_OFF 0u
#define X2_OFF (64u * 1024u)
#define C2_OFF (X2_OFF + 32u * 1024u)
#define XB_OFF (C2_OFF + 64u * 1024u)
#define CB_OFF (XB_OFF + (unsigned)NQ * DD * 2u)
#define WT_OFF (CB_OFF + (unsigned)MC * DD * 2u)
#define PART_OFF (WT_OFF + (unsigned)KK * DD * 2u)
#define WS_NEED ((size_t)PART_OFF + (size_t)NQ * 64 * 8)

__device__ __forceinline__ short f2bf(float f) {
  unsigned int u = __float_as_uint(f);
  u += 0x7FFFu + ((u >> 16) & 1u);
  return (short)(u >> 16);
}

__device__ __forceinline__ void gload_lds16(const void* g, void* l) {
  __builtin_amdgcn_global_load_lds(
      (__attribute__((address_space(1))) void*)(g),
      (__attribute__((address_space(3))) void*)(l), 16, 0, 0);
}

// ---- cast rows to bf16 + row sum-of-squares ----
__global__ __launch_bounds__(256) void prep_rows(const float* __restrict__ src,
                                                 short* __restrict__ dstb,
                                                 float* __restrict__ dst2) {
  const int lane = threadIdx.x & 63;
  const size_t row = (size_t)blockIdx.x * 4 + (threadIdx.x >> 6);
  const float4* p = (const float4*)(src + row * DD + lane * 8);
  float4 v0 = p[0], v1 = p[1];
  float s = v0.x * v0.x + v0.y * v0.y + v0.z * v0.z + v0.w * v0.w +
            v1.x * v1.x + v1.y * v1.y + v1.z * v1.z + v1.w * v1.w;
  short8 o;
  o[0] = f2bf(v0.x); o[1] = f2bf(v0.y); o[2] = f2bf(v0.z); o[3] = f2bf(v0.w);
  o[4] = f2bf(v1.x); o[5] = f2bf(v1.y); o[6] = f2bf(v1.z); o[7] = f2bf(v1.w);
  *(short8*)(dstb + row * DD + lane * 8) = o;
#pragma unroll
  for (int m = 32; m >= 1; m >>= 1) s += __shfl_xor(s, m, 64);
  if (lane == 0) dst2[row] = s;
}

// ---- transpose-cast W[d][j] -> wt[j][d] (bf16) ----
__global__ __launch_bounds__(256) void prep_w(const float* __restrict__ W,
                                              short* __restrict__ wt) {
  __shared__ float t[64][65];
  const int bx = blockIdx.x, by = blockIdx.y;
#pragma unroll
  for (int i = 0; i < 16; ++i) {
    int idx = i * 256 + threadIdx.x;
    int r = idx >> 6, c = idx & 63;
    t[r][c] = W[(size_t)(by * 64 + r) * KK + bx * 64 + c];
  }
  __syncthreads();
#pragma unroll
  for (int i = 0; i < 16; ++i) {
    int idx = i * 256 + threadIdx.x;
    int r = idx >> 6, c = idx & 63;
    wt[(size_t)(bx * 64 + r) * DD + by * 64 + c] = f2bf(t[c][r]);
  }
}

// ---- stage one 128x64 half-tile (linear LDS dest, inverse-swizzled src) ----
__device__ __forceinline__ void stage_half(const short* __restrict__ src,
                                           size_t grow0, int k0, short* lhalf,
                                           int wid, int lane) {
#pragma unroll
  for (int j = 0; j < 2; ++j) {
    const int pch = wid * 128 + j * 64 + lane;
    const int r = pch >> 3;
    const int c = (pch & 7) ^ (r & 7);
    gload_lds16(src + (grow0 + (size_t)r) * DD + k0 + c * 8,
                (char*)lhalf + (size_t)(wid * 128 + j * 64) * 16);
  }
}

__device__ __forceinline__ bf16x8 ld_frag(const short* lhalf, int row, int ks,
                                          int cr) {
  const int c = (ks * 4 + cr) ^ (row & 7);
  return *(const bf16x8*)(lhalf + row * 64 + c * 8);
}

__device__ __forceinline__ unsigned long long u64min(unsigned long long a,
                                                     unsigned long long b) {
  return a < b ? a : b;
}

// ---- main GEMM: 256x256 tile, 8 waves (2Mx4N), 8-phase, fused min epilogue --
// PATH 0: per-block partial write + separate reduce.  PATH 1: atomicMin.
template <int PATH>
__global__ __launch_bounds__(512, 2) void gemm_min(
    const short* __restrict__ xb, const short* __restrict__ cb,
    const float* __restrict__ x2, const float* __restrict__ c2,
    unsigned long long* __restrict__ part,
    unsigned long long* __restrict__ mink) {
  __shared__ short L[2][2][2][8192];  // [buf][A/B][half][128*64] = 128 KiB
  const int tid = threadIdx.x;
  const int lane = tid & 63;
  const int wid = tid >> 6;
  const int wr = wid >> 2, wc = wid & 3;  // 2x4 wave grid, per-wave 128x64
  const int cl = lane & 15, cr = lane >> 4;

  // XCD-aware 4x8 sub-tile mapping: 32 concurrent blocks/XCD share
  // 4 A-panels + 8 B-panels (~3 MB, fits the 4 MB per-XCD L2).
  const int bid = blockIdx.x;          // 0..2047
  const int xcd = bid & 7, k = bid >> 3;  // k in 0..255
  const int by = xcd * 4 + ((k & 31) >> 3);  // 0..31
  const int bx = ((k >> 5) << 3) + (k & 7);  // 0..63
  const size_t row0 = (size_t)by * 256;
  const size_t col0 = (size_t)bx * 256;

  f32x4 acc[8][4];
#pragma unroll
  for (int m = 0; m < 8; ++m)
#pragma unroll
    for (int n = 0; n < 4; ++n) acc[m][n] = (f32x4)0.0f;

  // prologue: 7 half-tiles in steady-state issue order, then vmcnt(6)
  stage_half(cb, col0, 0, &L[0][1][0][0], wid, lane);         // B0(0)
  stage_half(xb, row0, 0, &L[0][0][0][0], wid, lane);         // A0(0)
  stage_half(xb, row0 + 128, 0, &L[0][0][1][0], wid, lane);   // A1(0)
  stage_half(cb, col0 + 128, 0, &L[0][1][1][0], wid, lane);   // B1(0)
  stage_half(xb, row0, 64, &L[1][0][0][0], wid, lane);        // A0(1)
  stage_half(xb, row0 + 128, 64, &L[1][0][1][0], wid, lane);  // A1(1)
  stage_half(cb, col0, 64, &L[1][1][0][0], wid, lane);        // B0(1)
  asm volatile("s_waitcnt vmcnt(6)" ::: "memory");
  __builtin_amdgcn_s_barrier();

  for (int t = 0; t < 8; ++t) {
    const int p = t & 1;
    const short* lA = &L[p][0][wr][0];
    const short* lB = &L[p][1][wc >> 1][0];
    const int brow = (wc & 1) * 64;
    const int k1 = ((t + 1) & 7) * 64;
    const int k2 = ((t + 2) & 7) * 64;

    bf16x8 aLo[4][2], aHi[4][2], bLo[2][2], bHi[2][2];

    // -- phase A: read A-lo + B-lo; issue B1(t+1); MFMA quad (lo,lo) --
    // (B1 of tile t-1 was last read at phase C of t-1 -> safe to overwrite)
#pragma unroll
    for (int m = 0; m < 4; ++m)
#pragma unroll
      for (int ks = 0; ks < 2; ++ks)
        aLo[m][ks] = ld_frag(lA, m * 16 + cl, ks, cr);
#pragma unroll
    for (int n = 0; n < 2; ++n)
#pragma unroll
      for (int ks = 0; ks < 2; ++ks)
        bLo[n][ks] = ld_frag(lB, brow + n * 16 + cl, ks, cr);
    stage_half(cb, col0 + 128, k1, &L[p ^ 1][1][1][0], wid, lane);
    __builtin_amdgcn_s_barrier();
    asm volatile("s_waitcnt lgkmcnt(0)" ::: "memory");
    __builtin_amdgcn_sched_barrier(0);
    __builtin_amdgcn_s_setprio(1);
#pragma unroll
    for (int m = 0; m < 4; ++m)
#pragma unroll
      for (int n = 0; n < 2; ++n)
#pragma unroll
        for (int ks = 0; ks < 2; ++ks)
          acc[m][n] = __builtin_amdgcn_mfma_f32_16x16x32_bf16(
              aLo[m][ks], bLo[n][ks], acc[m][n], 0, 0, 0);
    __builtin_amdgcn_s_setprio(0);
    __builtin_amdgcn_s_barrier();

    // -- phase B: read A-hi; no stage; MFMA quad (hi,lo) --
#pragma unroll
    for (int m = 0; m < 4; ++m)
#pragma unroll
      for (int ks = 0; ks < 2; ++ks)
        aHi[m][ks] = ld_frag(lA, 64 + m * 16 + cl, ks, cr);
    __builtin_amdgcn_s_barrier();
    asm volatile("s_waitcnt lgkmcnt(0)" ::: "memory");
    __builtin_amdgcn_sched_barrier(0);
    __builtin_amdgcn_s_setprio(1);
#pragma unroll
    for (int m = 0; m < 4; ++m)
#pragma unroll
      for (int n = 0; n < 2; ++n)
#pragma unroll
        for (int ks = 0; ks < 2; ++ks)
          acc[4 + m][n] = __builtin_amdgcn_mfma_f32_16x16x32_bf16(
              aHi[m][ks], bLo[n][ks], acc[4 + m][n], 0, 0, 0);
    __builtin_amdgcn_s_setprio(0);
    __builtin_amdgcn_s_barrier();

    // -- phase C: read B-hi; issue A0(t+2)+A1(t+2) (A last read phase B) --
#pragma unroll
    for (int n = 0; n < 2; ++n)
#pragma unroll
      for (int ks = 0; ks < 2; ++ks)
        bHi[n][ks] = ld_frag(lB, brow + 32 + n * 16 + cl, ks, cr);
    stage_half(xb, row0, k2, &L[p][0][0][0], wid, lane);
    stage_half(xb, row0 + 128, k2, &L[p][0][1][0], wid, lane);
    __builtin_amdgcn_s_barrier();
    asm volatile("s_waitcnt lgkmcnt(0)" ::: "memory");
    __builtin_amdgcn_sched_barrier(0);
    __builtin_amdgcn_s_setprio(1);
#pragma unroll
    for (int m = 0; m < 4; ++m)
#pragma unroll
      for (int n = 0; n < 2; ++n)
#pragma unroll
        for (int ks = 0; ks < 2; ++ks)
          acc[m][2 + n] = __builtin_amdgcn_mfma_f32_16x16x32_bf16(
              aLo[m][ks], bHi[n][ks], acc[m][2 + n], 0, 0, 0);
    __builtin_amdgcn_s_setprio(0);
    __builtin_amdgcn_s_barrier();

    // -- phase D: issue B0(t+2) (B0 last read phase C); vmcnt(6) gates t+1 --
    stage_half(cb, col0, k2, &L[p][1][0][0], wid, lane);
    asm volatile("s_waitcnt vmcnt(6)" ::: "memory");
    __builtin_amdgcn_s_barrier();
    __builtin_amdgcn_s_setprio(1);
#pragma unroll
    for (int m = 0; m < 4; ++m)
#pragma unroll
      for (int n = 0; n < 2; ++n)
#pragma unroll
        for (int ks = 0; ks < 2; ++ks)
          acc[4 + m][2 + n] = __builtin_amdgcn_mfma_f32_16x16x32_bf16(
              aHi[m][ks], bHi[n][ks], acc[4 + m][2 + n], 0, 0, 0);
    __builtin_amdgcn_s_setprio(0);
    __builtin_amdgcn_s_barrier();
  }

  // drain ALL waves' wrapped prefetches before reusing LDS for the reduction
  asm volatile("s_waitcnt vmcnt(0)" ::: "memory");
  __syncthreads();

  // epilogue: d2 = x2 + c2 - 2S; pack (d2bits, col); 16-lane reduce;
  // cross-wave combine in LDS -> one u64 per row per block.
  unsigned long long* ls = (unsigned long long*)&L[0][0][0][0];  // [256][4]
  float c2v[4];
#pragma unroll
  for (int n = 0; n < 4; ++n) c2v[n] = c2[col0 + wc * 64 + n * 16 + cl];
#pragma unroll
  for (int m = 0; m < 8; ++m) {
#pragma unroll
    for (int r = 0; r < 4; ++r) {
      const int row_local = wr * 128 + m * 16 + cr * 4 + r;
      const float xv = x2[row0 + row_local];
      unsigned long long best = ~0ull;
#pragma unroll
      for (int n = 0; n < 4; ++n) {
        float d2 = fmaxf(xv + c2v[n] - 2.0f * acc[m][n][r], 0.0f);
        unsigned int col = (unsigned int)(col0 + wc * 64 + n * 16 + cl);
        unsigned long long key =
            ((unsigned long long)__float_as_uint(d2) << 32) | col;
        best = u64min(best, key);
      }
#pragma unroll
      for (int msk = 8; msk >= 1; msk >>= 1) {
        unsigned long long o = __shfl_xor(best, msk, 64);
        best = u64min(best, o);
      }
      if (cl == 0) ls[row_local * 4 + wc] = best;
    }
  }
  __syncthreads();
  if (tid < 256) {
    unsigned long long b = u64min(u64min(ls[tid * 4 + 0], ls[tid * 4 + 1]),
                                  u64min(ls[tid * 4 + 2], ls[tid * 4 + 3]));
    if (PATH == 0)
      part[(size_t)(row0 + tid) * 64 + bx] = b;
    else
      atomicMin(&mink[row0 + tid], b);
  }
}

// ---- final argmin reduce: mink[row] = min over 64 col-block partials ----
__global__ __launch_bounds__(256) void reduce_mink(
    const unsigned long long* __restrict__ part,
    unsigned long long* __restrict__ mink) {
  const int row = blockIdx.x * 256 + threadIdx.x;
  const unsigned long long* p = part + (size_t)row * 64;
  unsigned long long best = ~0ull;
#pragma unroll
  for (int j = 0; j < 64; ++j) best = best < p[j] ? best : p[j];
  mink[row] = best;
}

// ---- fallback GEMM: out = x @ W + b, cache-select epilogue ----
__global__ __launch_bounds__(256) void gemm_out(
    const short* __restrict__ xb, const short* __restrict__ wt,
    const float* __restrict__ bias, const float* __restrict__ cache_out,
    const unsigned long long* __restrict__ mink, float* __restrict__ out) {
  __shared__ short lA[128 * 64];
  __shared__ short lB[128 * 64];
  const int tid = threadIdx.x;
  const int lane = tid & 63;
  const int wid = tid >> 6;
  const int wr = wid >> 1, wc = wid & 1;
  const int cl = lane & 15, cr = lane >> 4;
  const size_t row0 = (size_t)blockIdx.y * 128;
  const size_t col0 = (size_t)blockIdx.x * 128;

  f32x4 acc[4][4];
#pragma unroll
  for (int m = 0; m < 4; ++m)
#pragma unroll
    for (int n = 0; n < 4; ++n) acc[m][n] = (f32x4)0.0f;

  for (int kt = 0; kt < DD / 64; ++kt) {
    const int k0 = kt * 64;
#pragma unroll
    for (int i = 0; i < 4; ++i) {
      const int cb0 = wid * 256 + i * 64;
      const int chunk = cb0 + lane;
      const int r = chunk >> 3, kc = chunk & 7;
      gload_lds16(xb + (row0 + r) * DD + k0 + kc * 8, (char*)lA + cb0 * 16);
      gload_lds16(wt + (col0 + r) * DD + k0 + kc * 8, (char*)lB + cb0 * 16);
    }
    __syncthreads();
#pragma unroll
    for (int ks = 0; ks < 2; ++ks) {
      bf16x8 a[4], b[4];
#pragma unroll
      for (int m = 0; m < 4; ++m)
        a[m] = *(const bf16x8*)(lA + (wr * 64 + m * 16 + cl) * 64 + ks * 32 + cr * 8);
#pragma unroll
      for (int n = 0; n < 4; ++n)
        b[n] = *(const bf16x8*)(lB + (wc * 64 + n * 16 + cl) * 64 + ks * 32 + cr * 8);
#pragma unroll
      for (int m = 0; m < 4; ++m)
#pragma unroll
        for (int n = 0; n < 4; ++n)
          acc[m][n] = __builtin_amdgcn_mfma_f32_16x16x32_bf16(a[m], b[n], acc[m][n], 0, 0, 0);
    }
    __syncthreads();
  }

#pragma unroll
  for (int m = 0; m < 4; ++m) {
#pragma unroll
    for (int r = 0; r < 4; ++r) {
      const size_t row = row0 + wr * 64 + m * 16 + cr * 4 + r;
      const unsigned long long key = mink[row];
      const float d2 = __uint_as_float((unsigned int)(key >> 32));
      const bool usec = (d2 <= 1e-4f);
      const unsigned int idx = (unsigned int)(key & 0xFFFFFFFFu);
#pragma unroll
      for (int n = 0; n < 4; ++n) {
        const size_t col = col0 + wc * 64 + n * 16 + cl;
        float v = acc[m][n][r] + bias[col];
        if (usec) v = cache_out[(size_t)idx * KK + col];
        out[row * KK + col] = v;
      }
    }
  }
}

extern "C" void kernel_launch(void* const* d_in, const int* in_sizes, int n_in,
                              void* d_out, int out_size, void* d_ws,
                              size_t ws_size, hipStream_t stream) {
  const float* x = (const float*)d_in[0];
  const float* cache_emb = (const float*)d_in[1];
  const float* cache_out = (const float*)d_in[2];
  const float* W = (const float*)d_in[3];
  const float* bias = (const float*)d_in[4];
  float* out = (float*)d_out;
  char* ws = (char*)d_ws;

  unsigned long long* mink = (unsigned long long*)(ws + MIN_OFF);
  float* x2 = (float*)(ws + X2_OFF);
  float* c2 = (float*)(ws + C2_OFF);
  short* xb = (short*)(ws + XB_OFF);
  short* cb = (short*)(ws + CB_OFF);
  short* wt = (short*)(ws + WT_OFF);
  unsigned long long* part = (unsigned long long*)(ws + PART_OFF);

  const bool use_part = (ws_size >= WS_NEED);

  prep_rows<<<NQ / 4, 256, 0, stream>>>(x, xb, x2);
  prep_rows<<<MC / 4, 256, 0, stream>>>(cache_emb, cb, c2);
  prep_w<<<dim3(KK / 64, DD / 64), 256, 0, stream>>>(W, wt);
  if (use_part) {
    gemm_min<0><<<(NQ / 256) * (MC / 256), 512, 0, stream>>>(xb, cb, x2, c2,
                                                             part, mink);
    reduce_mink<<<NQ / 256, 256, 0, stream>>>(part, mink);
  } else {
    hipMemsetAsync(mink, 0xFF, NQ * sizeof(unsigned long long), stream);
    gemm_min<1><<<(NQ / 256) * (MC / 256), 512, 0, stream>>>(xb, cb, x2, c2,
                                                             part, mink);
  }
  gemm_out<<<dim3(KK / 128, NQ / 128), 256, 0, stream>>>(xb, wt, bias,
                                                         cache_out, mink, out);
}

// Round 4
// 226.560 us; speedup vs baseline: 1.8642x; 1.0719x over previous
//
#include <hip/hip_runtime.h>
#include <hip/hip_bf16.h>
#include <cstdint>
#include <cstddef>

// out = where(min_dist(x, cache_emb) <= 0.01, cache_out[argmin], x@W+b)
// N=8192, M=16384, D=512, K=512, f32 in/out.
// gemm_min: 128x128 tile, 4 waves, BK=64, single-buffer LDS (32 KiB),
// 3 blocks/CU TLP, T2 swizzle, XCD-resident A-panels, low-contention argmin.

#define NQ 8192
#define MC 16384
#define DD 512
#define KK 512

typedef float f32x4 __attribute__((ext_vector_type(4)));
typedef __bf16 bf16x8 __attribute__((ext_vector_type(8)));
typedef short short8 __attribute__((ext_vector_type(8)));

// ---- workspace layout (bytes) ----
#define MIN_OFF 0u
#define X2_OFF (64u * 1024u)
#define C2_OFF (X2_OFF + 32u * 1024u)
#define XB_OFF (C2_OFF + 64u * 1024u)
#define CB_OFF (XB_OFF + (unsigned)NQ * DD * 2u)
#define WT_OFF (CB_OFF + (unsigned)MC * DD * 2u)
#define PART_OFF (WT_OFF + (unsigned)KK * DD * 2u)
// part: NQ x 64 u64 = 4 MB (same footprint as round 3 -> known to fit)

__device__ __forceinline__ short f2bf(float f) {
  unsigned int u = __float_as_uint(f);
  u += 0x7FFFu + ((u >> 16) & 1u);
  return (short)(u >> 16);
}

__device__ __forceinline__ float bf2f(short s) {
  unsigned int u = ((unsigned int)(unsigned short)s) << 16;
  return __uint_as_float(u);
}

__device__ __forceinline__ void gload_lds16(const void* g, void* l) {
  __builtin_amdgcn_global_load_lds(
      (__attribute__((address_space(1))) void*)(g),
      (__attribute__((address_space(3))) void*)(l), 16, 0, 0);
}

__device__ __forceinline__ unsigned long long u64min(unsigned long long a,
                                                     unsigned long long b) {
  return a < b ? a : b;
}

// ---- cast rows to bf16 + row sum-of-squares (from QUANTIZED values so an
// exact duplicate gives d2 == 0 exactly) ----
__global__ __launch_bounds__(256) void prep_rows(const float* __restrict__ src,
                                                 short* __restrict__ dstb,
                                                 float* __restrict__ dst2) {
  const int lane = threadIdx.x & 63;
  const size_t row = (size_t)blockIdx.x * 4 + (threadIdx.x >> 6);
  const float4* p = (const float4*)(src + row * DD + lane * 8);
  float4 v0 = p[0], v1 = p[1];
  short8 o;
  o[0] = f2bf(v0.x); o[1] = f2bf(v0.y); o[2] = f2bf(v0.z); o[3] = f2bf(v0.w);
  o[4] = f2bf(v1.x); o[5] = f2bf(v1.y); o[6] = f2bf(v1.z); o[7] = f2bf(v1.w);
  *(short8*)(dstb + row * DD + lane * 8) = o;
  float s = 0.f;
#pragma unroll
  for (int j = 0; j < 8; ++j) {
    float q = bf2f(o[j]);
    s += q * q;
  }
#pragma unroll
  for (int m = 32; m >= 1; m >>= 1) s += __shfl_xor(s, m, 64);
  if (lane == 0) dst2[row] = s;
}

// ---- transpose-cast W[d][j] -> wt[j][d] (bf16) ----
__global__ __launch_bounds__(256) void prep_w(const float* __restrict__ W,
                                              short* __restrict__ wt) {
  __shared__ float t[64][65];
  const int bx = blockIdx.x, by = blockIdx.y;
#pragma unroll
  for (int i = 0; i < 16; ++i) {
    int idx = i * 256 + threadIdx.x;
    int r = idx >> 6, c = idx & 63;
    t[r][c] = W[(size_t)(by * 64 + r) * KK + bx * 64 + c];
  }
  __syncthreads();
#pragma unroll
  for (int i = 0; i < 16; ++i) {
    int idx = i * 256 + threadIdx.x;
    int r = idx >> 6, c = idx & 63;
    wt[(size_t)(bx * 64 + r) * DD + by * 64 + c] = f2bf(t[c][r]);
  }
}

// Swizzle scheme (T2, rule #21 both-sides): physical 16B slot s of row r in
// LDS holds logical k-chunk s^(r&7); source address pre-applies the inverse;
// ds_read applies the same XOR. global_load_lds dest stays linear.

// per-thread global byte offsets for staging a 128x64 bf16 tile, 256 threads
__device__ __forceinline__ void stage_offs(unsigned go[4], size_t grow0,
                                           int wid, int lane) {
#pragma unroll
  for (int j = 0; j < 4; ++j) {
    const int ch = wid * 256 + j * 64 + lane;
    const int r = ch >> 3;
    const int c = (ch & 7) ^ (r & 7);
    go[j] = (unsigned)((grow0 + (size_t)r) * (DD * 2) + c * 16);
  }
}

__device__ __forceinline__ void stage_tile(const char* base,
                                           const unsigned go[4], unsigned kb,
                                           char* lds, int wid) {
#pragma unroll
  for (int j = 0; j < 4; ++j)
    gload_lds16(base + go[j] + kb, lds + (wid * 256 + j * 64) * 16);
}

__device__ __forceinline__ bf16x8 ld_frag(const short* lrow0, int m, int ks,
                                          int cr, int cl) {
  const int slot = (ks * 4 + cr) ^ (cl & 7);
  return *(const bf16x8*)(lrow0 + m * 16 * 64 + slot * 8);
}

// ---- main GEMM: 128x128 tile, 4 waves (2x2 of 64x64), fused min epilogue ---
__global__ __launch_bounds__(256, 3) void gemm_min(
    const short* __restrict__ xb, const short* __restrict__ cb,
    const float* __restrict__ x2, const float* __restrict__ c2,
    unsigned long long* __restrict__ part) {
  __shared__ short lA[128 * 64];
  __shared__ short lB[128 * 64];
  const int tid = threadIdx.x;
  const int lane = tid & 63;
  const int wid = tid >> 6;
  const int wr = wid >> 1, wc = wid & 1;
  const int cl = lane & 15, cr = lane >> 4;

  // XCD mapping: per XCD a fixed set of 8 A-panels (1 MB, L2-resident for the
  // whole kernel); B-panels walked in groups of 16 (2 MB per group).
  const int bid = blockIdx.x;               // 0..8191
  const int xcd = bid & 7;
  const int k = bid >> 3;                   // 0..1023
  const int by = xcd * 8 + ((k >> 4) & 7);  // 0..63
  const int bx = ((k >> 7) << 4) | (k & 15);  // 0..127
  const size_t row0 = (size_t)by * 128;
  const size_t col0 = (size_t)bx * 128;

  unsigned goA[4], goB[4];
  stage_offs(goA, row0, wid, lane);
  stage_offs(goB, col0, wid, lane);
  const char* xbp = (const char*)xb;
  const char* cbp = (const char*)cb;

  f32x4 acc[4][4];
#pragma unroll
  for (int m = 0; m < 4; ++m)
#pragma unroll
    for (int n = 0; n < 4; ++n) acc[m][n] = (f32x4)0.0f;

  const short* lArow = lA + (wr * 64 + cl) * 64;
  const short* lBrow = lB + (wc * 64 + cl) * 64;

  for (int kt = 0; kt < DD / 64; ++kt) {
    stage_tile(xbp, goA, (unsigned)kt * 128, (char*)lA, wid);
    stage_tile(cbp, goB, (unsigned)kt * 128, (char*)lB, wid);
    __syncthreads();
#pragma unroll
    for (int ks = 0; ks < 2; ++ks) {
      bf16x8 a[4], b[4];
#pragma unroll
      for (int m = 0; m < 4; ++m) a[m] = ld_frag(lArow, m, ks, cr, cl);
#pragma unroll
      for (int n = 0; n < 4; ++n) b[n] = ld_frag(lBrow, n, ks, cr, cl);
#pragma unroll
      for (int m = 0; m < 4; ++m)
#pragma unroll
        for (int n = 0; n < 4; ++n)
          acc[m][n] = __builtin_amdgcn_mfma_f32_16x16x32_bf16(a[m], b[n],
                                                              acc[m][n], 0, 0, 0);
    }
    __syncthreads();
  }

  // epilogue: d2 = x2 + c2 - 2S; pack (d2bits, col); 16-lane butterfly;
  // cross-wave LDS combine; one 2-way-contended atomicMin per row per block.
  unsigned long long* ls = (unsigned long long*)lA;  // [128][2]
  float c2v[4];
#pragma unroll
  for (int n = 0; n < 4; ++n) c2v[n] = c2[col0 + wc * 64 + n * 16 + cl];
#pragma unroll
  for (int m = 0; m < 4; ++m) {
#pragma unroll
    for (int r = 0; r < 4; ++r) {
      const int row_local = wr * 64 + m * 16 + cr * 4 + r;
      const float xv = x2[row0 + row_local];
      unsigned long long best = ~0ull;
#pragma unroll
      for (int n = 0; n < 4; ++n) {
        float d2 = fmaxf(xv + c2v[n] - 2.0f * acc[m][n][r], 0.0f);
        unsigned int col = (unsigned int)(col0 + wc * 64 + n * 16 + cl);
        unsigned long long key =
            ((unsigned long long)__float_as_uint(d2) << 32) | col;
        best = u64min(best, key);
      }
#pragma unroll
      for (int msk = 8; msk >= 1; msk >>= 1) {
        unsigned long long o = __shfl_xor(best, msk, 64);
        best = u64min(best, o);
      }
      if (cl == 0) ls[row_local * 2 + wc] = best;
    }
  }
  __syncthreads();
  if (tid < 128) {
    unsigned long long b = u64min(ls[tid * 2 + 0], ls[tid * 2 + 1]);
    atomicMin(&part[(size_t)(row0 + tid) * 64 + (bx >> 1)], b);
  }
}

// ---- final argmin reduce: mink[row] = min over 64 partials ----
__global__ __launch_bounds__(256) void reduce_mink(
    const unsigned long long* __restrict__ part,
    unsigned long long* __restrict__ mink) {
  const int row = blockIdx.x * 256 + threadIdx.x;
  const unsigned long long* p = part + (size_t)row * 64;
  unsigned long long best = ~0ull;
#pragma unroll
  for (int j = 0; j < 64; ++j) best = best < p[j] ? best : p[j];
  mink[row] = best;
}

// ---- fallback GEMM: out = x @ W + b, cache-select epilogue ----
__global__ __launch_bounds__(256, 3) void gemm_out(
    const short* __restrict__ xb, const short* __restrict__ wt,
    const float* __restrict__ bias, const float* __restrict__ cache_out,
    const unsigned long long* __restrict__ mink, float* __restrict__ out) {
  __shared__ short lA[128 * 64];
  __shared__ short lB[128 * 64];
  const int tid = threadIdx.x;
  const int lane = tid & 63;
  const int wid = tid >> 6;
  const int wr = wid >> 1, wc = wid & 1;
  const int cl = lane & 15, cr = lane >> 4;
  const size_t row0 = (size_t)blockIdx.y * 128;
  const size_t col0 = (size_t)blockIdx.x * 128;

  unsigned goA[4], goB[4];
  stage_offs(goA, row0, wid, lane);
  stage_offs(goB, col0, wid, lane);
  const char* xbp = (const char*)xb;
  const char* wtp = (const char*)wt;

  f32x4 acc[4][4];
#pragma unroll
  for (int m = 0; m < 4; ++m)
#pragma unroll
    for (int n = 0; n < 4; ++n) acc[m][n] = (f32x4)0.0f;

  const short* lArow = lA + (wr * 64 + cl) * 64;
  const short* lBrow = lB + (wc * 64 + cl) * 64;

  for (int kt = 0; kt < DD / 64; ++kt) {
    stage_tile(xbp, goA, (unsigned)kt * 128, (char*)lA, wid);
    stage_tile(wtp, goB, (unsigned)kt * 128, (char*)lB, wid);
    __syncthreads();
#pragma unroll
    for (int ks = 0; ks < 2; ++ks) {
      bf16x8 a[4], b[4];
#pragma unroll
      for (int m = 0; m < 4; ++m) a[m] = ld_frag(lArow, m, ks, cr, cl);
#pragma unroll
      for (int n = 0; n < 4; ++n) b[n] = ld_frag(lBrow, n, ks, cr, cl);
#pragma unroll
      for (int m = 0; m < 4; ++m)
#pragma unroll
        for (int n = 0; n < 4; ++n)
          acc[m][n] = __builtin_amdgcn_mfma_f32_16x16x32_bf16(a[m], b[n],
                                                              acc[m][n], 0, 0, 0);
    }
    __syncthreads();
  }

#pragma unroll
  for (int m = 0; m < 4; ++m) {
#pragma unroll
    for (int r = 0; r < 4; ++r) {
      const size_t row = row0 + wr * 64 + m * 16 + cr * 4 + r;
      const unsigned long long key = mink[row];
      const float d2 = __uint_as_float((unsigned int)(key >> 32));
      const bool usec = (d2 <= 1e-4f);
      const unsigned int idx = (unsigned int)(key & 0xFFFFFFFFu);
#pragma unroll
      for (int n = 0; n < 4; ++n) {
        const size_t col = col0 + wc * 64 + n * 16 + cl;
        float v = acc[m][n][r] + bias[col];
        if (usec) v = cache_out[(size_t)idx * KK + col];
        out[row * KK + col] = v;
      }
    }
  }
}

extern "C" void kernel_launch(void* const* d_in, const int* in_sizes, int n_in,
                              void* d_out, int out_size, void* d_ws,
                              size_t ws_size, hipStream_t stream) {
  const float* x = (const float*)d_in[0];
  const float* cache_emb = (const float*)d_in[1];
  const float* cache_out = (const float*)d_in[2];
  const float* W = (const float*)d_in[3];
  const float* bias = (const float*)d_in[4];
  float* out = (float*)d_out;
  char* ws = (char*)d_ws;

  unsigned long long* mink = (unsigned long long*)(ws + MIN_OFF);
  float* x2 = (float*)(ws + X2_OFF);
  float* c2 = (float*)(ws + C2_OFF);
  short* xb = (short*)(ws + XB_OFF);
  short* cb = (short*)(ws + CB_OFF);
  short* wt = (short*)(ws + WT_OFF);
  unsigned long long* part = (unsigned long long*)(ws + PART_OFF);

  hipMemsetAsync(part, 0xFF, (size_t)NQ * 64 * 8, stream);
  prep_rows<<<NQ / 4, 256, 0, stream>>>(x, xb, x2);
  prep_rows<<<MC / 4, 256, 0, stream>>>(cache_emb, cb, c2);
  prep_w<<<dim3(KK / 64, DD / 64), 256, 0, stream>>>(W, wt);
  gemm_min<<<(NQ / 128) * (MC / 128), 256, 0, stream>>>(xb, cb, x2, c2, part);
  reduce_mink<<<NQ / 256, 256, 0, stream>>>(part, mink);
  gemm_out<<<dim3(KK / 128, NQ / 128), 256, 0, stream>>>(xb, wt, bias,
                                                         cache_out, mink, out);
}